// Round 1
// baseline (124.290 us; speedup 1.0000x reference)
//
#include <hip/hip_runtime.h>

// Problem constants (match reference)
#define BB 32
#define CC 2
#define HH 480
#define WW 640
#define NA 4096
// S = 1.0, L = 0.5, W_EQ = 1.0, W_INEQ = 1.0

struct Accum {
    double loss_ineq;
    double loss_eq;
    unsigned long long num_ineq;
};

__global__ __launch_bounds__(256) void lrizz_main(
        const float* __restrict__ pred,
        const int* __restrict__ tgt,
        Accum* __restrict__ acc) {
    const int total = BB * NA;
    int t = blockIdx.x * blockDim.x + threadIdx.x;

    float li = 0.f, le = 0.f;
    int ni = 0;

    if (t < total) {
        int b = t >> 12;                    // NA = 4096
        const int* tp = tgt + (size_t)t * 7;
        int ca = tp[0], xa = tp[1], ya = tp[2];
        int cb = tp[3], xb = tp[4], yb = tp[5];
        int lab = tp[6];

        size_t base = (size_t)b * (CC * HH * WW);
        float pa = pred[base + ((size_t)ca * HH + (size_t)ya) * WW + (size_t)xa];
        float pb = pred[base + ((size_t)cb * HH + (size_t)yb) * WW + (size_t)xb];
        float diff = pb - pa;

        if (lab != 0) {
            // relu(S*L - S*diff*lab)^2 with S=1, L=0.5
            float v = 0.5f - diff * (float)lab;
            v = fmaxf(v, 0.f);
            li = v * v;
            ni = 1;
        } else {
            le = diff * diff;
        }
    }

    // wave (64-lane) butterfly reduce
    #pragma unroll
    for (int off = 32; off > 0; off >>= 1) {
        li += __shfl_down(li, off, 64);
        le += __shfl_down(le, off, 64);
        ni += __shfl_down(ni, off, 64);
    }

    __shared__ float s_li[4], s_le[4];
    __shared__ int   s_ni[4];
    int wid  = threadIdx.x >> 6;
    int lane = threadIdx.x & 63;
    if (lane == 0) { s_li[wid] = li; s_le[wid] = le; s_ni[wid] = ni; }
    __syncthreads();

    if (threadIdx.x == 0) {
        float tli = s_li[0] + s_li[1] + s_li[2] + s_li[3];
        float tle = s_le[0] + s_le[1] + s_le[2] + s_le[3];
        int   tni = s_ni[0] + s_ni[1] + s_ni[2] + s_ni[3];
        atomicAdd(&acc->loss_ineq, (double)tli);
        atomicAdd(&acc->loss_eq,  (double)tle);
        atomicAdd(&acc->num_ineq, (unsigned long long)tni);
    }
}

__global__ void lrizz_final(const Accum* __restrict__ acc, float* __restrict__ out) {
    const double total = (double)(BB * NA);
    double ni = (double)acc->num_ineq;
    double ne = total - ni;
    double r = 0.0;
    if (ni > 0.0) r += acc->loss_ineq / ni;   // W_INEQ = 1
    if (ne > 0.0) r += acc->loss_eq  / ne;    // W_EQ = 1
    out[0] = (float)r;
}

extern "C" void kernel_launch(void* const* d_in, const int* in_sizes, int n_in,
                              void* d_out, int out_size, void* d_ws, size_t ws_size,
                              hipStream_t stream) {
    const float* pred = (const float*)d_in[0];
    const int*   tgt  = (const int*)d_in[1];
    float* out = (float*)d_out;
    Accum* acc = (Accum*)d_ws;

    // ws is re-poisoned to 0xAA before every timed launch — zero it (capture-safe)
    hipMemsetAsync(acc, 0, sizeof(Accum), stream);

    const int total = BB * NA;           // 131072
    const int block = 256;
    const int grid  = total / block;     // 512
    lrizz_main<<<grid, block, 0, stream>>>(pred, tgt, acc);
    lrizz_final<<<1, 1, 0, stream>>>(acc, out);
}

// Round 3
// 106.066 us; speedup vs baseline: 1.1718x; 1.1718x over previous
//
#include <hip/hip_runtime.h>

// Problem constants (match reference)
#define BB 32
#define CC 2
#define HH 480
#define WW 640
#define NA 4096
// S = 1.0, L = 0.5, W_EQ = 1.0, W_INEQ = 1.0

#define GRID1 256
#define BLOCK1 256

// Stage 1: per-block partials {loss_ineq, loss_eq, num_ineq, unused} -> ws
__global__ __launch_bounds__(BLOCK1) void lrizz_main(
        const float* __restrict__ pred,
        const int* __restrict__ tgt,
        float4* __restrict__ partials) {
    const int total = BB * NA;                 // 131072
    const int stride = GRID1 * BLOCK1;         // 65536

    float li = 0.f, le = 0.f, ni = 0.f;

    for (int t = blockIdx.x * BLOCK1 + threadIdx.x; t < total; t += stride) {
        int b = t >> 12;                       // NA = 4096
        const int* tp = tgt + (size_t)t * 7;
        int ca = tp[0], xa = tp[1], ya = tp[2];
        int cb = tp[3], xb = tp[4], yb = tp[5];
        int lab = tp[6];

        size_t base = (size_t)b * (CC * HH * WW);
        float pa = pred[base + ((size_t)ca * HH + (size_t)ya) * WW + (size_t)xa];
        float pb = pred[base + ((size_t)cb * HH + (size_t)yb) * WW + (size_t)xb];
        float diff = pb - pa;

        if (lab != 0) {
            // relu(S*L - S*diff*lab)^2 with S=1, L=0.5
            float v = fmaxf(0.5f - diff * (float)lab, 0.f);
            li += v * v;
            ni += 1.f;
        } else {
            le += diff * diff;
        }
    }

    // 64-lane wave butterfly reduce
    #pragma unroll
    for (int off = 32; off > 0; off >>= 1) {
        li += __shfl_down(li, off, 64);
        le += __shfl_down(le, off, 64);
        ni += __shfl_down(ni, off, 64);
    }

    __shared__ float s_li[4], s_le[4], s_ni[4];
    int wid  = threadIdx.x >> 6;
    int lane = threadIdx.x & 63;
    if (lane == 0) { s_li[wid] = li; s_le[wid] = le; s_ni[wid] = ni; }
    __syncthreads();

    if (threadIdx.x == 0) {
        float4 p;
        p.x = s_li[0] + s_li[1] + s_li[2] + s_li[3];
        p.y = s_le[0] + s_le[1] + s_le[2] + s_le[3];
        p.z = s_ni[0] + s_ni[1] + s_ni[2] + s_ni[3];
        p.w = 0.f;
        partials[blockIdx.x] = p;
    }
}

// Stage 2: reduce 256 partials, normalize, write scalar
__global__ __launch_bounds__(GRID1) void lrizz_final(
        const float4* __restrict__ partials,
        float* __restrict__ out) {
    float4 p = partials[threadIdx.x];
    float li = p.x, le = p.y, ni = p.z;

    #pragma unroll
    for (int off = 32; off > 0; off >>= 1) {
        li += __shfl_down(li, off, 64);
        le += __shfl_down(le, off, 64);
        ni += __shfl_down(ni, off, 64);
    }

    __shared__ float s_li[4], s_le[4], s_ni[4];
    int wid  = threadIdx.x >> 6;
    int lane = threadIdx.x & 63;
    if (lane == 0) { s_li[wid] = li; s_le[wid] = le; s_ni[wid] = ni; }
    __syncthreads();

    if (threadIdx.x == 0) {
        double tli = (double)(s_li[0] + s_li[1] + s_li[2] + s_li[3]);
        double tle = (double)(s_le[0] + s_le[1] + s_le[2] + s_le[3]);
        double tni = (double)(s_ni[0] + s_ni[1] + s_ni[2] + s_ni[3]);
        double tne = (double)(BB * NA) - tni;
        double r = 0.0;
        if (tni > 0.0) r += tli / tni;   // W_INEQ = 1
        if (tne > 0.0) r += tle / tne;   // W_EQ = 1
        out[0] = (float)r;
    }
}

extern "C" void kernel_launch(void* const* d_in, const int* in_sizes, int n_in,
                              void* d_out, int out_size, void* d_ws, size_t ws_size,
                              hipStream_t stream) {
    const float* pred = (const float*)d_in[0];
    const int*   tgt  = (const int*)d_in[1];
    float* out = (float*)d_out;
    float4* partials = (float4*)d_ws;   // 256 * 16 B = 4 KB of scratch

    lrizz_main<<<GRID1, BLOCK1, 0, stream>>>(pred, tgt, partials);
    lrizz_final<<<1, GRID1, 0, stream>>>(partials, out);
}

// Round 5
// 104.478 us; speedup vs baseline: 1.1896x; 1.0152x over previous
//
#include <hip/hip_runtime.h>

// Problem constants (match reference)
#define BB 32
#define CC 2
#define HH 480
#define WW 640
#define NA 4096
// S = 1.0, L = 0.5, W_EQ = 1.0, W_INEQ = 1.0

#define GRID1 512
#define BLOCK1 256

struct TgtRow { int v[7]; };   // 28 B, 4-byte aligned; compiler emits dwordx4+x2+x1

// Stage 1: 1 annotation per thread -> per-block partials {li, le, ni, 0}
__global__ __launch_bounds__(BLOCK1) void lrizz_main(
        const float* __restrict__ pred,
        const int* __restrict__ tgt,
        float4* __restrict__ partials) {
    int t = blockIdx.x * BLOCK1 + threadIdx.x;      // grid exactly covers 131072
    int b = t >> 12;                                 // NA = 4096

    TgtRow r = ((const TgtRow*)tgt)[t];
    int ca = r.v[0], xa = r.v[1], ya = r.v[2];
    int cb = r.v[3], xb = r.v[4], yb = r.v[5];
    int lab = r.v[6];

    size_t base = (size_t)b * (CC * HH * WW);
    // issue both gathers back-to-back before any use
    float pa = pred[base + ((size_t)ca * HH + (size_t)ya) * WW + (size_t)xa];
    float pb = pred[base + ((size_t)cb * HH + (size_t)yb) * WW + (size_t)xb];
    float diff = pb - pa;

    float li = 0.f, le = 0.f, ni = 0.f;
    if (lab != 0) {
        // relu(S*L - S*diff*lab)^2 with S=1, L=0.5
        float v = fmaxf(0.5f - diff * (float)lab, 0.f);
        li = v * v;
        ni = 1.f;
    } else {
        le = diff * diff;
    }

    // 64-lane wave butterfly reduce
    #pragma unroll
    for (int off = 32; off > 0; off >>= 1) {
        li += __shfl_down(li, off, 64);
        le += __shfl_down(le, off, 64);
        ni += __shfl_down(ni, off, 64);
    }

    __shared__ float s_li[4], s_le[4], s_ni[4];
    int wid  = threadIdx.x >> 6;
    int lane = threadIdx.x & 63;
    if (lane == 0) { s_li[wid] = li; s_le[wid] = le; s_ni[wid] = ni; }
    __syncthreads();

    if (threadIdx.x == 0) {
        float4 p;
        p.x = s_li[0] + s_li[1] + s_li[2] + s_li[3];
        p.y = s_le[0] + s_le[1] + s_le[2] + s_le[3];
        p.z = s_ni[0] + s_ni[1] + s_ni[2] + s_ni[3];
        p.w = 0.f;
        partials[blockIdx.x] = p;
    }
}

// Stage 2: reduce 512 partials (2 per thread), normalize, write scalar
__global__ __launch_bounds__(256) void lrizz_final(
        const float4* __restrict__ partials,
        float* __restrict__ out) {
    float4 p0 = partials[threadIdx.x];
    float4 p1 = partials[threadIdx.x + 256];
    float li = p0.x + p1.x, le = p0.y + p1.y, ni = p0.z + p1.z;

    #pragma unroll
    for (int off = 32; off > 0; off >>= 1) {
        li += __shfl_down(li, off, 64);
        le += __shfl_down(le, off, 64);
        ni += __shfl_down(ni, off, 64);
    }

    __shared__ float s_li[4], s_le[4], s_ni[4];
    int wid  = threadIdx.x >> 6;
    int lane = threadIdx.x & 63;
    if (lane == 0) { s_li[wid] = li; s_le[wid] = le; s_ni[wid] = ni; }
    __syncthreads();

    if (threadIdx.x == 0) {
        double tli = (double)(s_li[0] + s_li[1] + s_li[2] + s_li[3]);
        double tle = (double)(s_le[0] + s_le[1] + s_le[2] + s_le[3]);
        double tni = (double)(s_ni[0] + s_ni[1] + s_ni[2] + s_ni[3]);
        double tne = (double)(BB * NA) - tni;
        double r = 0.0;
        if (tni > 0.0) r += tli / tni;   // W_INEQ = 1
        if (tne > 0.0) r += tle / tne;   // W_EQ = 1
        out[0] = (float)r;
    }
}

extern "C" void kernel_launch(void* const* d_in, const int* in_sizes, int n_in,
                              void* d_out, int out_size, void* d_ws, size_t ws_size,
                              hipStream_t stream) {
    const float* pred = (const float*)d_in[0];
    const int*   tgt  = (const int*)d_in[1];
    float* out = (float*)d_out;
    float4* partials = (float4*)d_ws;   // 512 * 16 B = 8 KB of scratch

    lrizz_main<<<GRID1, BLOCK1, 0, stream>>>(pred, tgt, partials);
    lrizz_final<<<1, 256, 0, stream>>>(partials, out);
}